// Round 2
// baseline (434.767 us; speedup 1.0000x reference)
//
#include <hip/hip_runtime.h>
#include <hip/hip_bf16.h>

#define N_NODES 20000
#define N_EDGES 640000
#define D_NODE  128
#define D_EDGE  64
#define D_OUT   128

// ---------------------------------------------------------------------------
// k_prep: WnT[k][o] = Wn[o][k]; ce[k] = sum_o Wa[256+o] * We[o][k]
// ---------------------------------------------------------------------------
__global__ __launch_bounds__(256) void k_prep(const float* __restrict__ Wn,
                                              const float* __restrict__ We,
                                              const float* __restrict__ Wa,
                                              float* __restrict__ WnT,
                                              float* __restrict__ ce) {
    int t = threadIdx.x;
    for (int idx = t; idx < D_OUT * D_NODE; idx += 256) {
        int o = idx / D_NODE, k = idx % D_NODE;
        WnT[k * D_OUT + o] = Wn[o * D_NODE + k];
    }
    if (t < D_EDGE) {
        float acc = 0.f;
        for (int o = 0; o < D_OUT; ++o)
            acc += Wa[2 * D_OUT + o] * We[o * D_EDGE + t];
        ce[t] = acc;
    }
}

// ---------------------------------------------------------------------------
// k_zgemm: z[n][o] = sum_k feats[n][k] * WnT[k][o]
//          ssrc[n] = sum_o z[n][o]*Wa[o]; sdst[n] = sum_o z[n][o]*Wa[128+o]
// block: 256 threads, 32 nodes per block; 4x4 register tile per thread
// LDS: WnT half-tile 64x128 (32KB) + feats 32x128 (16KB) = 48KB
// ---------------------------------------------------------------------------
__global__ __launch_bounds__(256) void k_zgemm(const float* __restrict__ feats,
                                               const float* __restrict__ wT,
                                               const float* __restrict__ Wa,
                                               float* __restrict__ z,
                                               float* __restrict__ ssrc,
                                               float* __restrict__ sdst) {
    __shared__ float sW[64 * 128];
    __shared__ float sF[32 * 128];
    int t = threadIdx.x;
    int nb = blockIdx.x * 32;

    const float4* fsrc = (const float4*)(feats + (size_t)nb * D_NODE);
    float4* fdst = (float4*)sF;
    for (int i = t; i < 32 * 32; i += 256) fdst[i] = fsrc[i];

    float acc[4][4] = {{0.f}};
    int o0 = (t & 31) * 4;
    int n0 = (t >> 5) * 4;

    for (int p = 0; p < 2; ++p) {
        __syncthreads();
        const float4* wsrc = (const float4*)(wT + p * 64 * 128);
        float4* wdst = (float4*)sW;
        for (int i = t; i < 64 * 32; i += 256) wdst[i] = wsrc[i];
        __syncthreads();
        for (int kk = 0; kk < 64; kk += 4) {
            float4 w0 = *(const float4*)(sW + (kk + 0) * 128 + o0);
            float4 w1 = *(const float4*)(sW + (kk + 1) * 128 + o0);
            float4 w2 = *(const float4*)(sW + (kk + 2) * 128 + o0);
            float4 w3 = *(const float4*)(sW + (kk + 3) * 128 + o0);
#pragma unroll
            for (int j = 0; j < 4; ++j) {
                float4 f = *(const float4*)(sF + (n0 + j) * 128 + p * 64 + kk);
                acc[j][0] += f.x * w0.x + f.y * w1.x + f.z * w2.x + f.w * w3.x;
                acc[j][1] += f.x * w0.y + f.y * w1.y + f.z * w2.y + f.w * w3.y;
                acc[j][2] += f.x * w0.z + f.y * w1.z + f.z * w2.z + f.w * w3.z;
                acc[j][3] += f.x * w0.w + f.y * w1.w + f.z * w2.w + f.w * w3.w;
            }
        }
    }

    float as0 = Wa[o0 + 0], as1 = Wa[o0 + 1], as2 = Wa[o0 + 2], as3 = Wa[o0 + 3];
    float ad0 = Wa[128 + o0 + 0], ad1 = Wa[128 + o0 + 1],
          ad2 = Wa[128 + o0 + 2], ad3 = Wa[128 + o0 + 3];
#pragma unroll
    for (int j = 0; j < 4; ++j) {
        int n = nb + n0 + j;
        *(float4*)(z + (size_t)n * D_OUT + o0) =
            make_float4(acc[j][0], acc[j][1], acc[j][2], acc[j][3]);
        float ps = acc[j][0] * as0 + acc[j][1] * as1 + acc[j][2] * as2 + acc[j][3] * as3;
        float pd = acc[j][0] * ad0 + acc[j][1] * ad1 + acc[j][2] * ad2 + acc[j][3] * ad3;
#pragma unroll
        for (int off = 16; off; off >>= 1) {
            ps += __shfl_xor(ps, off, 32);
            pd += __shfl_xor(pd, off, 32);
        }
        if ((t & 31) == 0) { ssrc[n] = ps; sdst[n] = pd; }
    }
}

// ---------------------------------------------------------------------------
// k_edge: e[j] = leaky_relu(feats_edge[j].ce + ssrc[src[j]] + sdst[dst[j]])
//         deg[dst[j]]++  (histogram for CSR)
// ---------------------------------------------------------------------------
__global__ __launch_bounds__(256) void k_edge(const float* __restrict__ fe,
                                              const float* __restrict__ ce,
                                              const float* __restrict__ ssrc,
                                              const float* __restrict__ sdst,
                                              const int* __restrict__ src,
                                              const int* __restrict__ dst,
                                              float* __restrict__ e,
                                              int* __restrict__ deg) {
    int j = blockIdx.x * 256 + threadIdx.x;
    const float4* row = (const float4*)(fe + (size_t)j * D_EDGE);
    const float4* c4 = (const float4*)ce;
    float acc = 0.f;
#pragma unroll
    for (int i = 0; i < D_EDGE / 4; ++i) {
        float4 f = row[i];
        float4 c = c4[i];
        acc += f.x * c.x + f.y * c.y + f.z * c.z + f.w * c.w;
    }
    int sj = src[j], dj = dst[j];
    float x = acc + ssrc[sj] + sdst[dj];
    e[j] = x > 0.f ? x : 0.2f * x;
    atomicAdd(&deg[dj], 1);
}

// ---------------------------------------------------------------------------
// k_scan: exclusive scan of deg[20000] -> offsets[20001], copy -> cursor
// single block, 1024 threads
// ---------------------------------------------------------------------------
__global__ __launch_bounds__(1024) void k_scan(const int* __restrict__ deg,
                                               int* __restrict__ offsets,
                                               int* __restrict__ cursor) {
    __shared__ int wsum[16];
    __shared__ int sCarry;
    __shared__ int sTotal;
    int t = threadIdx.x, lane = t & 63, wv = t >> 6;
    if (t == 0) sCarry = 0;
    __syncthreads();
    for (int base = 0; base < N_NODES; base += 1024) {
        int idx = base + t;
        int v = (idx < N_NODES) ? deg[idx] : 0;
        int x = v;
#pragma unroll
        for (int d = 1; d < 64; d <<= 1) {
            int y = __shfl_up(x, d, 64);
            if (lane >= d) x += y;
        }
        if (lane == 63) wsum[wv] = x;
        __syncthreads();
        if (t == 0) {
            int a = 0;
            for (int i = 0; i < 16; ++i) { int tmp = wsum[i]; wsum[i] = a; a += tmp; }
            sTotal = a;
        }
        __syncthreads();
        int excl = x - v + wsum[wv] + sCarry;
        if (idx < N_NODES) { offsets[idx] = excl; cursor[idx] = excl; }
        __syncthreads();
        if (t == 0) sCarry += sTotal;
        __syncthreads();
    }
    if (t == 0) offsets[N_NODES] = sCarry;
}

// ---------------------------------------------------------------------------
// k_fill: CSR fill (order within a segment nondeterministic -> only affects
// fp rounding order, within tolerance)
// ---------------------------------------------------------------------------
__global__ __launch_bounds__(256) void k_fill(const int* __restrict__ dst,
                                              int* __restrict__ cursor,
                                              int* __restrict__ edge_list) {
    int j = blockIdx.x * 256 + threadIdx.x;
    int d = dst[j];
    int pos = atomicAdd(&cursor[d], 1);
    edge_list[pos] = j;
}

// ---------------------------------------------------------------------------
// k_gather: per node: m = max e, s = sum exp(e-m), h = sum alpha * z[src]
// block = 128 threads (one per output dim), 2 waves
// ---------------------------------------------------------------------------
#define ECACHE 8
__global__ __launch_bounds__(128) void k_gather(const int* __restrict__ offsets,
                                                const int* __restrict__ edge_list,
                                                const float* __restrict__ e,
                                                const int* __restrict__ src,
                                                const float* __restrict__ z,
                                                float* __restrict__ h) {
    __shared__ float wLds[128];
    __shared__ int sLds[128];
    __shared__ float red[2];
    int n = blockIdx.x, t = threadIdx.x;
    int beg = offsets[n], end = offsets[n + 1];

    float ecache[ECACHE];
    float lmax = -3.4e38f;
    {
        int c = 0;
        for (int i = beg + t; i < end; i += 128, ++c) {
            float ej = e[edge_list[i]];
            if (c < ECACHE) ecache[c] = ej;
            lmax = fmaxf(lmax, ej);
        }
    }
#pragma unroll
    for (int off = 32; off; off >>= 1) lmax = fmaxf(lmax, __shfl_xor(lmax, off, 64));
    if ((t & 63) == 0) red[t >> 6] = lmax;
    __syncthreads();
    float m = fmaxf(red[0], red[1]);
    __syncthreads();

    float lsum = 0.f;
    {
        int c = 0;
        for (int i = beg + t; i < end; i += 128, ++c) {
            float ej = (c < ECACHE) ? ecache[c] : e[edge_list[i]];
            lsum += expf(ej - m);
        }
    }
#pragma unroll
    for (int off = 32; off; off >>= 1) lsum += __shfl_xor(lsum, off, 64);
    if ((t & 63) == 0) red[t >> 6] = lsum;
    __syncthreads();
    float s = red[0] + red[1];
    float inv = (s > 0.f) ? 1.f / s : 0.f;

    float acc = 0.f;
    for (int chunk = beg; chunk < end; chunk += 128) {
        int cnt = min(128, end - chunk);
        __syncthreads();
        if (t < cnt) {
            int j = edge_list[chunk + t];
            wLds[t] = expf(e[j] - m) * inv;
            sLds[t] = src[j];
        }
        __syncthreads();
        int q = 0;
        for (; q + 4 <= cnt; q += 4) {
            float a0 = wLds[q + 0] * z[(size_t)sLds[q + 0] * D_OUT + t];
            float a1 = wLds[q + 1] * z[(size_t)sLds[q + 1] * D_OUT + t];
            float a2 = wLds[q + 2] * z[(size_t)sLds[q + 2] * D_OUT + t];
            float a3 = wLds[q + 3] * z[(size_t)sLds[q + 3] * D_OUT + t];
            acc += a0 + a1 + a2 + a3;
        }
        for (; q < cnt; ++q) acc += wLds[q] * z[(size_t)sLds[q] * D_OUT + t];
    }
    h[(size_t)n * D_OUT + t] = acc;
}

extern "C" void kernel_launch(void* const* d_in, const int* in_sizes, int n_in,
                              void* d_out, int out_size, void* d_ws, size_t ws_size,
                              hipStream_t stream) {
    const float* feats_node = (const float*)d_in[0];
    const float* feats_edge = (const float*)d_in[1];
    const float* Wn = (const float*)d_in[2];
    const float* We = (const float*)d_in[3];
    const float* Wa = (const float*)d_in[4];
    const int* src = (const int*)d_in[5];
    const int* dst = (const int*)d_in[6];
    float* h = (float*)d_out;

    // workspace layout (all 16B-aligned by construction)
    float* WnT  = (float*)d_ws;                 // 16384
    float* ce   = WnT + 16384;                  // 64
    float* z    = ce + 64;                      // 2,560,000
    float* ssrc = z + (size_t)N_NODES * D_OUT;  // 20000
    float* sdst = ssrc + N_NODES;               // 20000
    float* e    = sdst + N_NODES;               // 640000
    int* deg       = (int*)(e + N_EDGES);       // 20000
    int* offsets   = deg + N_NODES;             // 20001
    int* cursor    = offsets + N_NODES + 1;     // 20000
    int* edge_list = cursor + N_NODES;          // 640000

    (void)hipMemsetAsync(deg, 0, N_NODES * sizeof(int), stream);

    k_prep<<<1, 256, 0, stream>>>(Wn, We, Wa, WnT, ce);
    k_zgemm<<<N_NODES / 32, 256, 0, stream>>>(feats_node, WnT, Wa, z, ssrc, sdst);
    k_edge<<<N_EDGES / 256, 256, 0, stream>>>(feats_edge, ce, ssrc, sdst, src, dst, e, deg);
    k_scan<<<1, 1024, 0, stream>>>(deg, offsets, cursor);
    k_fill<<<N_EDGES / 256, 256, 0, stream>>>(dst, cursor, edge_list);
    k_gather<<<N_NODES, 128, 0, stream>>>(offsets, edge_list, e, src, z, h);
}

// Round 3
// 425.689 us; speedup vs baseline: 1.0213x; 1.0213x over previous
//
#include <hip/hip_runtime.h>
#include <hip/hip_bf16.h>

#define N_NODES 20000
#define N_EDGES 640000
#define D_NODE  128
#define D_EDGE  64
#define D_OUT   128

// ---------------------------------------------------------------------------
// k_prep_hist: all blocks histogram dst -> deg; block 0 additionally builds
// WnT (transpose of Wn) and ce = We^T @ a_e.
// ---------------------------------------------------------------------------
__global__ __launch_bounds__(256) void k_prep_hist(const float* __restrict__ Wn,
                                                   const float* __restrict__ We,
                                                   const float* __restrict__ Wa,
                                                   const int* __restrict__ dst,
                                                   float* __restrict__ WnT,
                                                   float* __restrict__ ce,
                                                   int* __restrict__ deg) {
    int t = threadIdx.x;
    int j = blockIdx.x * 256 + t;
    atomicAdd(&deg[dst[j]], 1);
    if (blockIdx.x == 0) {
        for (int idx = t; idx < D_OUT * D_NODE; idx += 256) {
            int o = idx >> 7, k = idx & 127;
            WnT[k * D_OUT + o] = Wn[idx];
        }
        if (t < D_EDGE) {
            float a = 0.f;
            for (int o = 0; o < D_OUT; ++o)
                a += Wa[2 * D_OUT + o] * We[o * D_EDGE + t];
            ce[t] = a;
        }
    }
}

// ---------------------------------------------------------------------------
// k_scan: single-round thread-coarsened exclusive scan. 1024 threads x 20
// elements each (20480 >= 20000). One wave-scan + one barrier round instead
// of 20 serial rounds.
// ---------------------------------------------------------------------------
__global__ __launch_bounds__(1024) void k_scan(const int* __restrict__ deg,
                                               int* __restrict__ offsets,
                                               int* __restrict__ cursor) {
    __shared__ int wsum[16];
    __shared__ int woff[16];
    const int PER = 20;
    int t = threadIdx.x, lane = t & 63, wv = t >> 6;
    int base = t * PER;
    int v[PER];
    int tsum = 0;
#pragma unroll
    for (int i = 0; i < PER; ++i) {
        int idx = base + i;
        v[i] = (idx < N_NODES) ? deg[idx] : 0;
        tsum += v[i];
    }
    int x = tsum;
#pragma unroll
    for (int d = 1; d < 64; d <<= 1) {
        int y = __shfl_up(x, d, 64);
        if (lane >= d) x += y;
    }
    if (lane == 63) wsum[wv] = x;
    __syncthreads();
    if (t == 0) {
        int a = 0;
        for (int i = 0; i < 16; ++i) { int tmp = wsum[i]; woff[i] = a; a += tmp; }
        offsets[N_NODES] = a;
    }
    __syncthreads();
    int run = (x - tsum) + woff[wv];
#pragma unroll
    for (int i = 0; i < PER; ++i) {
        int idx = base + i;
        if (idx < N_NODES) { offsets[idx] = run; cursor[idx] = run; }
        run += v[i];
    }
}

// ---------------------------------------------------------------------------
// k_zgemm: z[n][o] = feats[n][:] @ WnT[:][o]; fused per-node attention
// scalars ssrc/sdst. 32 nodes/block, 4x4 register tile, 48KB LDS.
// ---------------------------------------------------------------------------
__global__ __launch_bounds__(256) void k_zgemm(const float* __restrict__ feats,
                                               const float* __restrict__ wT,
                                               const float* __restrict__ Wa,
                                               float* __restrict__ z,
                                               float* __restrict__ ssrc,
                                               float* __restrict__ sdst) {
    __shared__ float sW[64 * 128];
    __shared__ float sF[32 * 128];
    int t = threadIdx.x;
    int nb = blockIdx.x * 32;

    const float4* fsrc = (const float4*)(feats + (size_t)nb * D_NODE);
    float4* fdst = (float4*)sF;
    for (int i = t; i < 32 * 32; i += 256) fdst[i] = fsrc[i];

    float acc[4][4] = {{0.f}};
    int o0 = (t & 31) * 4;
    int n0 = (t >> 5) * 4;

    for (int p = 0; p < 2; ++p) {
        __syncthreads();
        const float4* wsrc = (const float4*)(wT + p * 64 * 128);
        float4* wdst = (float4*)sW;
        for (int i = t; i < 64 * 32; i += 256) wdst[i] = wsrc[i];
        __syncthreads();
        for (int kk = 0; kk < 64; kk += 4) {
            float4 w0 = *(const float4*)(sW + (kk + 0) * 128 + o0);
            float4 w1 = *(const float4*)(sW + (kk + 1) * 128 + o0);
            float4 w2 = *(const float4*)(sW + (kk + 2) * 128 + o0);
            float4 w3 = *(const float4*)(sW + (kk + 3) * 128 + o0);
#pragma unroll
            for (int j = 0; j < 4; ++j) {
                float4 f = *(const float4*)(sF + (n0 + j) * 128 + p * 64 + kk);
                acc[j][0] += f.x * w0.x + f.y * w1.x + f.z * w2.x + f.w * w3.x;
                acc[j][1] += f.x * w0.y + f.y * w1.y + f.z * w2.y + f.w * w3.y;
                acc[j][2] += f.x * w0.z + f.y * w1.z + f.z * w2.z + f.w * w3.z;
                acc[j][3] += f.x * w0.w + f.y * w1.w + f.z * w2.w + f.w * w3.w;
            }
        }
    }

    float as0 = Wa[o0 + 0], as1 = Wa[o0 + 1], as2 = Wa[o0 + 2], as3 = Wa[o0 + 3];
    float ad0 = Wa[128 + o0 + 0], ad1 = Wa[128 + o0 + 1],
          ad2 = Wa[128 + o0 + 2], ad3 = Wa[128 + o0 + 3];
#pragma unroll
    for (int j = 0; j < 4; ++j) {
        int n = nb + n0 + j;
        *(float4*)(z + (size_t)n * D_OUT + o0) =
            make_float4(acc[j][0], acc[j][1], acc[j][2], acc[j][3]);
        float ps = acc[j][0] * as0 + acc[j][1] * as1 + acc[j][2] * as2 + acc[j][3] * as3;
        float pd = acc[j][0] * ad0 + acc[j][1] * ad1 + acc[j][2] * ad2 + acc[j][3] * ad3;
#pragma unroll
        for (int off = 16; off; off >>= 1) {
            ps += __shfl_xor(ps, off, 32);
            pd += __shfl_xor(pd, off, 32);
        }
        if ((t & 31) == 0) { ssrc[n] = ps; sdst[n] = pd; }
    }
}

// ---------------------------------------------------------------------------
// k_edge_fill: per edge: logit -> leaky_relu -> CSR slot via cursor atomic,
// scatter-write packed {e, src} (one 8B store). Fuses old k_edge + k_fill;
// eliminates the e[] round-trip and edge_list indirection.
// ---------------------------------------------------------------------------
__global__ __launch_bounds__(256) void k_edge_fill(const float* __restrict__ fe,
                                                   const float* __restrict__ ce,
                                                   const float* __restrict__ ssrc,
                                                   const float* __restrict__ sdst,
                                                   const int* __restrict__ src,
                                                   const int* __restrict__ dst,
                                                   int* __restrict__ cursor,
                                                   float2* __restrict__ es) {
    int j = blockIdx.x * 256 + threadIdx.x;
    const float4* row = (const float4*)(fe + (size_t)j * D_EDGE);
    const float4* c4 = (const float4*)ce;
    float acc = 0.f;
#pragma unroll
    for (int i = 0; i < D_EDGE / 4; ++i) {
        float4 f = row[i];
        float4 c = c4[i];
        acc += f.x * c.x + f.y * c.y + f.z * c.z + f.w * c.w;
    }
    int sj = src[j], dj = dst[j];
    float x = acc + ssrc[sj] + sdst[dj];
    float ev = x > 0.f ? x : 0.2f * x;
    int pos = atomicAdd(&cursor[dj], 1);
    es[pos] = make_float2(ev, __int_as_float(sj));
}

// ---------------------------------------------------------------------------
// k_gather: per node (block=128, one thread per out dim): linear reads of
// es[beg:end] (register-cached up to deg 512), softmax, then coalesced
// 512B z-row gathers weighted by alpha.
// ---------------------------------------------------------------------------
__global__ __launch_bounds__(128) void k_gather(const int* __restrict__ offsets,
                                                const float2* __restrict__ es,
                                                const float* __restrict__ z,
                                                float* __restrict__ h) {
    __shared__ float wLds[128];
    __shared__ int sLds[128];
    __shared__ float red[2];
    int n = blockIdx.x, t = threadIdx.x;
    int beg = offsets[n], end = offsets[n + 1];

    float2 cache[4];
    float lmax = -3.4e38f;
    {
        int c = 0;
        for (int i = beg + t; i < end; i += 128, ++c) {
            float2 v = es[i];
            if (c < 4) cache[c] = v;
            lmax = fmaxf(lmax, v.x);
        }
    }
#pragma unroll
    for (int off = 32; off; off >>= 1) lmax = fmaxf(lmax, __shfl_xor(lmax, off, 64));
    if ((t & 63) == 0) red[t >> 6] = lmax;
    __syncthreads();
    float m = fmaxf(red[0], red[1]);
    __syncthreads();

    float lsum = 0.f;
    {
        int c = 0;
        for (int i = beg + t; i < end; i += 128, ++c) {
            float ex = (c < 4) ? cache[c].x : es[i].x;
            lsum += expf(ex - m);
        }
    }
#pragma unroll
    for (int off = 32; off; off >>= 1) lsum += __shfl_xor(lsum, off, 64);
    if ((t & 63) == 0) red[t >> 6] = lsum;
    __syncthreads();
    float s = red[0] + red[1];
    float inv = (s > 0.f) ? 1.f / s : 0.f;

    float acc = 0.f;
    for (int chunk = beg; chunk < end; chunk += 128) {
        int cnt = min(128, end - chunk);
        __syncthreads();
        if (t < cnt) {
            int c = (chunk - beg) >> 7;
            float2 v = (c < 4) ? cache[c] : es[chunk + t];
            wLds[t] = expf(v.x - m) * inv;
            sLds[t] = __float_as_int(v.y);
        }
        __syncthreads();
        int q = 0;
        for (; q + 4 <= cnt; q += 4) {
            float a0 = wLds[q + 0] * z[(size_t)sLds[q + 0] * D_OUT + t];
            float a1 = wLds[q + 1] * z[(size_t)sLds[q + 1] * D_OUT + t];
            float a2 = wLds[q + 2] * z[(size_t)sLds[q + 2] * D_OUT + t];
            float a3 = wLds[q + 3] * z[(size_t)sLds[q + 3] * D_OUT + t];
            acc += a0 + a1 + a2 + a3;
        }
        for (; q < cnt; ++q) acc += wLds[q] * z[(size_t)sLds[q] * D_OUT + t];
    }
    h[(size_t)n * D_OUT + t] = acc;
}

extern "C" void kernel_launch(void* const* d_in, const int* in_sizes, int n_in,
                              void* d_out, int out_size, void* d_ws, size_t ws_size,
                              hipStream_t stream) {
    const float* feats_node = (const float*)d_in[0];
    const float* feats_edge = (const float*)d_in[1];
    const float* Wn = (const float*)d_in[2];
    const float* We = (const float*)d_in[3];
    const float* Wa = (const float*)d_in[4];
    const int* src = (const int*)d_in[5];
    const int* dst = (const int*)d_in[6];
    float* h = (float*)d_out;

    // workspace layout (float2 region 8B-aligned: offset 2,616,448 is even)
    float* WnT  = (float*)d_ws;                 // 16384
    float* ce   = WnT + 16384;                  // 64
    float* z    = ce + 64;                      // 2,560,000
    float* ssrc = z + (size_t)N_NODES * D_OUT;  // 20000
    float* sdst = ssrc + N_NODES;               // 20000
    float2* es  = (float2*)(sdst + N_NODES);    // 640000 float2
    int* deg       = (int*)(es + N_EDGES);      // 20000
    int* offsets   = deg + N_NODES;             // 20001
    int* cursor    = offsets + N_NODES + 1;     // 20000

    (void)hipMemsetAsync(deg, 0, N_NODES * sizeof(int), stream);

    k_prep_hist<<<N_EDGES / 256, 256, 0, stream>>>(Wn, We, Wa, dst, WnT, ce, deg);
    k_scan<<<1, 1024, 0, stream>>>(deg, offsets, cursor);
    k_zgemm<<<N_NODES / 32, 256, 0, stream>>>(feats_node, WnT, Wa, z, ssrc, sdst);
    k_edge_fill<<<N_EDGES / 256, 256, 0, stream>>>(feats_edge, ce, ssrc, sdst, src, dst, cursor, es);
    k_gather<<<N_NODES, 128, 0, stream>>>(offsets, es, z, h);
}

// Round 4
// 397.506 us; speedup vs baseline: 1.0937x; 1.0709x over previous
//
#include <hip/hip_runtime.h>
#include <hip/hip_bf16.h>

#define N_NODES 20000
#define N_EDGES 640000
#define D_NODE  128
#define D_EDGE  64
#define D_OUT   128

// ---------------------------------------------------------------------------
// k_hist_rank: rank[j] = position of edge j within its dst segment (atomic
// histogram — the ONLY atomics in the pipeline, 1 per edge, in a kernel that
// reads just dst (2.5 MB)). Block 0 also builds WnT and ce = We^T a_e.
// ---------------------------------------------------------------------------
__global__ __launch_bounds__(256) void k_hist_rank(const int* __restrict__ dst,
                                                   const float* __restrict__ Wn,
                                                   const float* __restrict__ We,
                                                   const float* __restrict__ Wa,
                                                   int* __restrict__ deg,
                                                   int* __restrict__ rank,
                                                   float* __restrict__ WnT,
                                                   float* __restrict__ ce) {
    int t = threadIdx.x;
    int j = blockIdx.x * 256 + t;
    rank[j] = atomicAdd(&deg[dst[j]], 1);
    if (blockIdx.x == 0) {
        for (int idx = t; idx < D_OUT * D_NODE; idx += 256) {
            int o = idx >> 7, k = idx & 127;
            WnT[k * D_OUT + o] = Wn[idx];
        }
        if (t < D_EDGE) {
            float a = 0.f;
            for (int o = 0; o < D_OUT; ++o)
                a += Wa[2 * D_OUT + o] * We[o * D_EDGE + t];
            ce[t] = a;
        }
    }
}

// ---------------------------------------------------------------------------
// k_scan: single-round thread-coarsened exclusive scan (1024 x 20 elems).
// ---------------------------------------------------------------------------
__global__ __launch_bounds__(1024) void k_scan(const int* __restrict__ deg,
                                               int* __restrict__ offsets) {
    __shared__ int wsum[16];
    __shared__ int woff[16];
    const int PER = 20;
    int t = threadIdx.x, lane = t & 63, wv = t >> 6;
    int base = t * PER;
    int v[PER];
    int tsum = 0;
#pragma unroll
    for (int i = 0; i < PER; ++i) {
        int idx = base + i;
        v[i] = (idx < N_NODES) ? deg[idx] : 0;
        tsum += v[i];
    }
    int x = tsum;
#pragma unroll
    for (int d = 1; d < 64; d <<= 1) {
        int y = __shfl_up(x, d, 64);
        if (lane >= d) x += y;
    }
    if (lane == 63) wsum[wv] = x;
    __syncthreads();
    if (t == 0) {
        int a = 0;
        for (int i = 0; i < 16; ++i) { int tmp = wsum[i]; woff[i] = a; a += tmp; }
        offsets[N_NODES] = a;
    }
    __syncthreads();
    int run = (x - tsum) + woff[wv];
#pragma unroll
    for (int i = 0; i < PER; ++i) {
        int idx = base + i;
        if (idx < N_NODES) offsets[idx] = run;
        run += v[i];
    }
}

// ---------------------------------------------------------------------------
// k_zgemm: z = feats @ WnT with fused per-node attention scalars. Unchanged
// from the passing R3 version.
// ---------------------------------------------------------------------------
__global__ __launch_bounds__(256) void k_zgemm(const float* __restrict__ feats,
                                               const float* __restrict__ wT,
                                               const float* __restrict__ Wa,
                                               float* __restrict__ z,
                                               float* __restrict__ ssrc,
                                               float* __restrict__ sdst) {
    __shared__ float sW[64 * 128];
    __shared__ float sF[32 * 128];
    int t = threadIdx.x;
    int nb = blockIdx.x * 32;

    const float4* fsrc = (const float4*)(feats + (size_t)nb * D_NODE);
    float4* fdst = (float4*)sF;
    for (int i = t; i < 32 * 32; i += 256) fdst[i] = fsrc[i];

    float acc[4][4] = {{0.f}};
    int o0 = (t & 31) * 4;
    int n0 = (t >> 5) * 4;

    for (int p = 0; p < 2; ++p) {
        __syncthreads();
        const float4* wsrc = (const float4*)(wT + p * 64 * 128);
        float4* wdst = (float4*)sW;
        for (int i = t; i < 64 * 32; i += 256) wdst[i] = wsrc[i];
        __syncthreads();
        for (int kk = 0; kk < 64; kk += 4) {
            float4 w0 = *(const float4*)(sW + (kk + 0) * 128 + o0);
            float4 w1 = *(const float4*)(sW + (kk + 1) * 128 + o0);
            float4 w2 = *(const float4*)(sW + (kk + 2) * 128 + o0);
            float4 w3 = *(const float4*)(sW + (kk + 3) * 128 + o0);
#pragma unroll
            for (int j = 0; j < 4; ++j) {
                float4 f = *(const float4*)(sF + (n0 + j) * 128 + p * 64 + kk);
                acc[j][0] += f.x * w0.x + f.y * w1.x + f.z * w2.x + f.w * w3.x;
                acc[j][1] += f.x * w0.y + f.y * w1.y + f.z * w2.y + f.w * w3.y;
                acc[j][2] += f.x * w0.z + f.y * w1.z + f.z * w2.z + f.w * w3.z;
                acc[j][3] += f.x * w0.w + f.y * w1.w + f.z * w2.w + f.w * w3.w;
            }
        }
    }

    float as0 = Wa[o0 + 0], as1 = Wa[o0 + 1], as2 = Wa[o0 + 2], as3 = Wa[o0 + 3];
    float ad0 = Wa[128 + o0 + 0], ad1 = Wa[128 + o0 + 1],
          ad2 = Wa[128 + o0 + 2], ad3 = Wa[128 + o0 + 3];
#pragma unroll
    for (int j = 0; j < 4; ++j) {
        int n = nb + n0 + j;
        *(float4*)(z + (size_t)n * D_OUT + o0) =
            make_float4(acc[j][0], acc[j][1], acc[j][2], acc[j][3]);
        float ps = acc[j][0] * as0 + acc[j][1] * as1 + acc[j][2] * as2 + acc[j][3] * as3;
        float pd = acc[j][0] * ad0 + acc[j][1] * ad1 + acc[j][2] * ad2 + acc[j][3] * ad3;
#pragma unroll
        for (int off = 16; off; off >>= 1) {
            ps += __shfl_xor(ps, off, 32);
            pd += __shfl_xor(pd, off, 32);
        }
        if ((t & 31) == 0) { ssrc[n] = ps; sdst[n] = pd; }
    }
}

// ---------------------------------------------------------------------------
// k_edge: 4 threads per edge, fully coalesced (each wave instr = contiguous
// 1KB of feats_edge). Atomic-free: pos = offsets[dst] + rank. One 8B scatter
// store of {e, src} per edge.
// ---------------------------------------------------------------------------
__global__ __launch_bounds__(256) void k_edge(const float* __restrict__ fe,
                                              const float* __restrict__ ce,
                                              const float* __restrict__ ssrc,
                                              const float* __restrict__ sdst,
                                              const int* __restrict__ src,
                                              const int* __restrict__ dst,
                                              const int* __restrict__ rank,
                                              const int* __restrict__ offsets,
                                              float2* __restrict__ es) {
    int t = threadIdx.x;
    int j = blockIdx.x * 64 + (t >> 2);   // edge index
    int part = t & 3;                     // 16-float slice of the 64-float row
    const float4* row = (const float4*)(fe + (size_t)j * D_EDGE + part * 16);
    const float4* c4 = (const float4*)(ce + part * 16);
    float acc = 0.f;
#pragma unroll
    for (int i = 0; i < 4; ++i) {
        float4 f = row[i];
        float4 c = c4[i];
        acc += f.x * c.x + f.y * c.y + f.z * c.z + f.w * c.w;
    }
    acc += __shfl_xor(acc, 1, 64);
    acc += __shfl_xor(acc, 2, 64);
    if (part == 0) {
        int sj = src[j], dj = dst[j];
        float x = acc + ssrc[sj] + sdst[dj];
        float ev = x > 0.f ? x : 0.2f * x;
        int pos = offsets[dj] + rank[j];
        es[pos] = make_float2(ev, __int_as_float(sj));
    }
}

// ---------------------------------------------------------------------------
// k_gather: per node (block=128): softmax over linear es[beg:end] (register-
// cached), then float4 weighted gather of z rows: 4 row-groups x 32 threads,
// 16B/lane, 2-deep unroll; 4-way LDS reduction at the end.
// ---------------------------------------------------------------------------
__global__ __launch_bounds__(128) void k_gather(const int* __restrict__ offsets,
                                                const float2* __restrict__ es,
                                                const float* __restrict__ z,
                                                float* __restrict__ h) {
    __shared__ float wLds[128];
    __shared__ int sLds[128];
    __shared__ float red[2];
    __shared__ float sRed[4][128];
    int n = blockIdx.x, t = threadIdx.x;
    int beg = offsets[n], end = offsets[n + 1];

    float2 cache[4];
    float lmax = -3.4e38f;
    {
        int c = 0;
        for (int i = beg + t; i < end; i += 128, ++c) {
            float2 v = es[i];
            if (c < 4) cache[c] = v;
            lmax = fmaxf(lmax, v.x);
        }
    }
#pragma unroll
    for (int off = 32; off; off >>= 1) lmax = fmaxf(lmax, __shfl_xor(lmax, off, 64));
    if ((t & 63) == 0) red[t >> 6] = lmax;
    __syncthreads();
    float m = fmaxf(red[0], red[1]);
    __syncthreads();

    float lsum = 0.f;
    {
        int c = 0;
        for (int i = beg + t; i < end; i += 128, ++c) {
            float ex = (c < 4) ? cache[c].x : es[i].x;
            lsum += expf(ex - m);
        }
    }
#pragma unroll
    for (int off = 32; off; off >>= 1) lsum += __shfl_xor(lsum, off, 64);
    if ((t & 63) == 0) red[t >> 6] = lsum;
    __syncthreads();
    float s = red[0] + red[1];
    float inv = (s > 0.f) ? 1.f / s : 0.f;

    int g = t >> 5;        // row group 0..3
    int c = t & 31;        // column quad: floats 4c..4c+3
    float4 a0 = make_float4(0.f, 0.f, 0.f, 0.f);
    float4 a1 = make_float4(0.f, 0.f, 0.f, 0.f);

    for (int chunk = beg; chunk < end; chunk += 128) {
        int cnt = min(128, end - chunk);
        __syncthreads();
        if (t < cnt) {
            int cc = (chunk - beg) >> 7;
            float2 v = (cc < 4) ? cache[cc] : es[chunk + t];
            wLds[t] = expf(v.x - m) * inv;
            sLds[t] = __float_as_int(v.y);
        }
        __syncthreads();
        int r = g;
        for (; r + 4 < cnt; r += 8) {
            float w0 = wLds[r];
            const float4 zv0 = *(const float4*)(z + (size_t)sLds[r] * D_OUT + c * 4);
            float w1 = wLds[r + 4];
            const float4 zv1 = *(const float4*)(z + (size_t)sLds[r + 4] * D_OUT + c * 4);
            a0.x += w0 * zv0.x; a0.y += w0 * zv0.y; a0.z += w0 * zv0.z; a0.w += w0 * zv0.w;
            a1.x += w1 * zv1.x; a1.y += w1 * zv1.y; a1.z += w1 * zv1.z; a1.w += w1 * zv1.w;
        }
        if (r < cnt) {
            float w0 = wLds[r];
            const float4 zv0 = *(const float4*)(z + (size_t)sLds[r] * D_OUT + c * 4);
            a0.x += w0 * zv0.x; a0.y += w0 * zv0.y; a0.z += w0 * zv0.z; a0.w += w0 * zv0.w;
        }
    }
    a0.x += a1.x; a0.y += a1.y; a0.z += a1.z; a0.w += a1.w;
    *(float4*)&sRed[g][c * 4] = a0;
    __syncthreads();
    h[(size_t)n * D_OUT + t] = sRed[0][t] + sRed[1][t] + sRed[2][t] + sRed[3][t];
}

extern "C" void kernel_launch(void* const* d_in, const int* in_sizes, int n_in,
                              void* d_out, int out_size, void* d_ws, size_t ws_size,
                              hipStream_t stream) {
    const float* feats_node = (const float*)d_in[0];
    const float* feats_edge = (const float*)d_in[1];
    const float* Wn = (const float*)d_in[2];
    const float* We = (const float*)d_in[3];
    const float* Wa = (const float*)d_in[4];
    const int* src = (const int*)d_in[5];
    const int* dst = (const int*)d_in[6];
    float* h = (float*)d_out;

    // workspace layout
    float* WnT  = (float*)d_ws;                 // 16384
    float* ce   = WnT + 16384;                  // 64
    float* z    = ce + 64;                      // 2,560,000
    float* ssrc = z + (size_t)N_NODES * D_OUT;  // 20000
    float* sdst = ssrc + N_NODES;               // 20000
    float2* es  = (float2*)(sdst + N_NODES);    // 640000 float2 (8B-aligned)
    int* deg     = (int*)(es + N_EDGES);        // 20000
    int* offsets = deg + N_NODES;               // 20001
    int* rank    = offsets + N_NODES + 1;       // 640000

    (void)hipMemsetAsync(deg, 0, N_NODES * sizeof(int), stream);

    k_hist_rank<<<N_EDGES / 256, 256, 0, stream>>>(dst, Wn, We, Wa, deg, rank, WnT, ce);
    k_scan<<<1, 1024, 0, stream>>>(deg, offsets);
    k_zgemm<<<N_NODES / 32, 256, 0, stream>>>(feats_node, WnT, Wa, z, ssrc, sdst);
    k_edge<<<N_EDGES / 64, 256, 0, stream>>>(feats_edge, ce, ssrc, sdst, src, dst, rank, offsets, es);
    k_gather<<<N_NODES, 128, 0, stream>>>(offsets, es, z, h);
}

// Round 5
// 395.865 us; speedup vs baseline: 1.0983x; 1.0041x over previous
//
#include <hip/hip_runtime.h>
#include <hip/hip_bf16.h>

#define N_NODES 20000
#define N_EDGES 640000
#define D_NODE  128
#define D_EDGE  64
#define D_OUT   128

// ---------------------------------------------------------------------------
// k_hist_rank: rank[j] = position of edge j within its dst segment (atomic
// histogram). Block 0 also builds WnT and ce = We^T a_e.
// ---------------------------------------------------------------------------
__global__ __launch_bounds__(256) void k_hist_rank(const int* __restrict__ dst,
                                                   const float* __restrict__ Wn,
                                                   const float* __restrict__ We,
                                                   const float* __restrict__ Wa,
                                                   int* __restrict__ deg,
                                                   int* __restrict__ rank,
                                                   float* __restrict__ WnT,
                                                   float* __restrict__ ce) {
    int t = threadIdx.x;
    int j = blockIdx.x * 256 + t;
    rank[j] = atomicAdd(&deg[dst[j]], 1);
    if (blockIdx.x == 0) {
        for (int idx = t; idx < D_OUT * D_NODE; idx += 256) {
            int o = idx >> 7, k = idx & 127;
            WnT[k * D_OUT + o] = Wn[idx];
        }
        if (t < D_EDGE) {
            float a = 0.f;
            for (int o = 0; o < D_OUT; ++o)
                a += Wa[2 * D_OUT + o] * We[o * D_EDGE + t];
            ce[t] = a;
        }
    }
}

// ---------------------------------------------------------------------------
// k_scan: single-round thread-coarsened exclusive scan (1024 x 20 elems).
// ---------------------------------------------------------------------------
__global__ __launch_bounds__(1024) void k_scan(const int* __restrict__ deg,
                                               int* __restrict__ offsets) {
    __shared__ int wsum[16];
    __shared__ int woff[16];
    const int PER = 20;
    int t = threadIdx.x, lane = t & 63, wv = t >> 6;
    int base = t * PER;
    int v[PER];
    int tsum = 0;
#pragma unroll
    for (int i = 0; i < PER; ++i) {
        int idx = base + i;
        v[i] = (idx < N_NODES) ? deg[idx] : 0;
        tsum += v[i];
    }
    int x = tsum;
#pragma unroll
    for (int d = 1; d < 64; d <<= 1) {
        int y = __shfl_up(x, d, 64);
        if (lane >= d) x += y;
    }
    if (lane == 63) wsum[wv] = x;
    __syncthreads();
    if (t == 0) {
        int a = 0;
        for (int i = 0; i < 16; ++i) { int tmp = wsum[i]; woff[i] = a; a += tmp; }
        offsets[N_NODES] = a;
    }
    __syncthreads();
    int run = (x - tsum) + woff[wv];
#pragma unroll
    for (int i = 0; i < PER; ++i) {
        int idx = base + i;
        if (idx < N_NODES) offsets[idx] = run;
        run += v[i];
    }
}

// ---------------------------------------------------------------------------
// k_zgemm: z = feats @ WnT with fused per-node attention scalars.
// ---------------------------------------------------------------------------
__global__ __launch_bounds__(256) void k_zgemm(const float* __restrict__ feats,
                                               const float* __restrict__ wT,
                                               const float* __restrict__ Wa,
                                               float* __restrict__ z,
                                               float* __restrict__ ssrc,
                                               float* __restrict__ sdst) {
    __shared__ float sW[64 * 128];
    __shared__ float sF[32 * 128];
    int t = threadIdx.x;
    int nb = blockIdx.x * 32;

    const float4* fsrc = (const float4*)(feats + (size_t)nb * D_NODE);
    float4* fdst = (float4*)sF;
    for (int i = t; i < 32 * 32; i += 256) fdst[i] = fsrc[i];

    float acc[4][4] = {{0.f}};
    int o0 = (t & 31) * 4;
    int n0 = (t >> 5) * 4;

    for (int p = 0; p < 2; ++p) {
        __syncthreads();
        const float4* wsrc = (const float4*)(wT + p * 64 * 128);
        float4* wdst = (float4*)sW;
        for (int i = t; i < 64 * 32; i += 256) wdst[i] = wsrc[i];
        __syncthreads();
        for (int kk = 0; kk < 64; kk += 4) {
            float4 w0 = *(const float4*)(sW + (kk + 0) * 128 + o0);
            float4 w1 = *(const float4*)(sW + (kk + 1) * 128 + o0);
            float4 w2 = *(const float4*)(sW + (kk + 2) * 128 + o0);
            float4 w3 = *(const float4*)(sW + (kk + 3) * 128 + o0);
#pragma unroll
            for (int j = 0; j < 4; ++j) {
                float4 f = *(const float4*)(sF + (n0 + j) * 128 + p * 64 + kk);
                acc[j][0] += f.x * w0.x + f.y * w1.x + f.z * w2.x + f.w * w3.x;
                acc[j][1] += f.x * w0.y + f.y * w1.y + f.z * w2.y + f.w * w3.y;
                acc[j][2] += f.x * w0.z + f.y * w1.z + f.z * w2.z + f.w * w3.z;
                acc[j][3] += f.x * w0.w + f.y * w1.w + f.z * w2.w + f.w * w3.w;
            }
        }
    }

    float as0 = Wa[o0 + 0], as1 = Wa[o0 + 1], as2 = Wa[o0 + 2], as3 = Wa[o0 + 3];
    float ad0 = Wa[128 + o0 + 0], ad1 = Wa[128 + o0 + 1],
          ad2 = Wa[128 + o0 + 2], ad3 = Wa[128 + o0 + 3];
#pragma unroll
    for (int j = 0; j < 4; ++j) {
        int n = nb + n0 + j;
        *(float4*)(z + (size_t)n * D_OUT + o0) =
            make_float4(acc[j][0], acc[j][1], acc[j][2], acc[j][3]);
        float ps = acc[j][0] * as0 + acc[j][1] * as1 + acc[j][2] * as2 + acc[j][3] * as3;
        float pd = acc[j][0] * ad0 + acc[j][1] * ad1 + acc[j][2] * ad2 + acc[j][3] * ad3;
#pragma unroll
        for (int off = 16; off; off >>= 1) {
            ps += __shfl_xor(ps, off, 32);
            pd += __shfl_xor(pd, off, 32);
        }
        if ((t & 31) == 0) { ssrc[n] = ps; sdst[n] = pd; }
    }
}

// ---------------------------------------------------------------------------
// k_edge: 4 threads per edge, fully coalesced; atomic-free CSR placement
// pos = offsets[dst] + rank. One 8B scatter store {e, src} per edge.
// ---------------------------------------------------------------------------
__global__ __launch_bounds__(256) void k_edge(const float* __restrict__ fe,
                                              const float* __restrict__ ce,
                                              const float* __restrict__ ssrc,
                                              const float* __restrict__ sdst,
                                              const int* __restrict__ src,
                                              const int* __restrict__ dst,
                                              const int* __restrict__ rank,
                                              const int* __restrict__ offsets,
                                              float2* __restrict__ es) {
    int t = threadIdx.x;
    int j = blockIdx.x * 64 + (t >> 2);
    int part = t & 3;
    const float4* row = (const float4*)(fe + (size_t)j * D_EDGE + part * 16);
    const float4* c4 = (const float4*)(ce + part * 16);
    float acc = 0.f;
#pragma unroll
    for (int i = 0; i < 4; ++i) {
        float4 f = row[i];
        float4 c = c4[i];
        acc += f.x * c.x + f.y * c.y + f.z * c.z + f.w * c.w;
    }
    acc += __shfl_xor(acc, 1, 64);
    acc += __shfl_xor(acc, 2, 64);
    if (part == 0) {
        int sj = src[j], dj = dst[j];
        float x = acc + ssrc[sj] + sdst[dj];
        float ev = x > 0.f ? x : 0.2f * x;
        int pos = offsets[dj] + rank[j];
        es[pos] = make_float2(ev, __int_as_float(sj));
    }
}

// ---------------------------------------------------------------------------
// k_gather: ONE WAVE PER NODE, zero barriers, zero LDS. Lane l owns edge
// beg+l (chunked by 64 for deg>64). Softmax via 64-lane butterflies; weight
// and src broadcast per edge via __shfl; z-row gathered as 64 lanes x float2
// (one coalesced 512B load per edge), 4-deep unrolled. 4 nodes per block.
// ---------------------------------------------------------------------------
__global__ __launch_bounds__(256) void k_gather(const int* __restrict__ offsets,
                                                const float2* __restrict__ es,
                                                const float* __restrict__ z,
                                                float* __restrict__ h) {
    int lane = threadIdx.x & 63;
    int n = blockIdx.x * 4 + (threadIdx.x >> 6);
    int beg = offsets[n], end = offsets[n + 1];

    // chunk 0 cached in registers (covers deg <= 64, i.e. ~all nodes)
    float2 v0 = make_float2(-3.4e38f, 0.f);
    int i0 = beg + lane;
    if (i0 < end) v0 = es[i0];
    float lmax = v0.x;
    for (int base = beg + 64; base < end; base += 64) {
        int i = base + lane;
        lmax = fmaxf(lmax, (i < end) ? es[i].x : -3.4e38f);
    }
#pragma unroll
    for (int off = 32; off; off >>= 1) lmax = fmaxf(lmax, __shfl_xor(lmax, off, 64));
    float m = lmax;

    float w0 = (i0 < end) ? __expf(v0.x - m) : 0.f;
    float lsum = w0;
    for (int base = beg + 64; base < end; base += 64) {
        int i = base + lane;
        lsum += (i < end) ? __expf(es[i].x - m) : 0.f;
    }
#pragma unroll
    for (int off = 32; off; off >>= 1) lsum += __shfl_xor(lsum, off, 64);
    float inv = (lsum > 0.f) ? 1.f / lsum : 0.f;

    float accx = 0.f, accy = 0.f;
    {
        int cnt = min(64, end - beg);
        float wl = w0 * inv;
        int sl = __float_as_int(v0.y);
        int r = 0;
        for (; r + 4 <= cnt; r += 4) {
            float wr0 = __shfl(wl, r + 0, 64); int sr0 = __shfl(sl, r + 0, 64);
            float wr1 = __shfl(wl, r + 1, 64); int sr1 = __shfl(sl, r + 1, 64);
            float wr2 = __shfl(wl, r + 2, 64); int sr2 = __shfl(sl, r + 2, 64);
            float wr3 = __shfl(wl, r + 3, 64); int sr3 = __shfl(sl, r + 3, 64);
            float2 z0 = *(const float2*)(z + (size_t)sr0 * D_OUT + lane * 2);
            float2 z1 = *(const float2*)(z + (size_t)sr1 * D_OUT + lane * 2);
            float2 z2 = *(const float2*)(z + (size_t)sr2 * D_OUT + lane * 2);
            float2 z3 = *(const float2*)(z + (size_t)sr3 * D_OUT + lane * 2);
            accx += wr0 * z0.x + wr1 * z1.x + wr2 * z2.x + wr3 * z3.x;
            accy += wr0 * z0.y + wr1 * z1.y + wr2 * z2.y + wr3 * z3.y;
        }
        for (; r < cnt; ++r) {
            float wr = __shfl(wl, r, 64); int sr = __shfl(sl, r, 64);
            float2 zv = *(const float2*)(z + (size_t)sr * D_OUT + lane * 2);
            accx += wr * zv.x; accy += wr * zv.y;
        }
    }
    for (int base = beg + 64; base < end; base += 64) {
        int i = base + lane;
        float2 v = (i < end) ? es[i] : make_float2(0.f, 0.f);
        float wl = (i < end) ? __expf(v.x - m) * inv : 0.f;
        int sl = __float_as_int(v.y);
        int cnt = min(64, end - base);
        int r = 0;
        for (; r + 4 <= cnt; r += 4) {
            float wr0 = __shfl(wl, r + 0, 64); int sr0 = __shfl(sl, r + 0, 64);
            float wr1 = __shfl(wl, r + 1, 64); int sr1 = __shfl(sl, r + 1, 64);
            float wr2 = __shfl(wl, r + 2, 64); int sr2 = __shfl(sl, r + 2, 64);
            float wr3 = __shfl(wl, r + 3, 64); int sr3 = __shfl(sl, r + 3, 64);
            float2 z0 = *(const float2*)(z + (size_t)sr0 * D_OUT + lane * 2);
            float2 z1 = *(const float2*)(z + (size_t)sr1 * D_OUT + lane * 2);
            float2 z2 = *(const float2*)(z + (size_t)sr2 * D_OUT + lane * 2);
            float2 z3 = *(const float2*)(z + (size_t)sr3 * D_OUT + lane * 2);
            accx += wr0 * z0.x + wr1 * z1.x + wr2 * z2.x + wr3 * z3.x;
            accy += wr0 * z0.y + wr1 * z1.y + wr2 * z2.y + wr3 * z3.y;
        }
        for (; r < cnt; ++r) {
            float wr = __shfl(wl, r, 64); int sr = __shfl(sl, r, 64);
            float2 zv = *(const float2*)(z + (size_t)sr * D_OUT + lane * 2);
            accx += wr * zv.x; accy += wr * zv.y;
        }
    }
    *(float2*)(h + (size_t)n * D_OUT + lane * 2) = make_float2(accx, accy);
}

extern "C" void kernel_launch(void* const* d_in, const int* in_sizes, int n_in,
                              void* d_out, int out_size, void* d_ws, size_t ws_size,
                              hipStream_t stream) {
    const float* feats_node = (const float*)d_in[0];
    const float* feats_edge = (const float*)d_in[1];
    const float* Wn = (const float*)d_in[2];
    const float* We = (const float*)d_in[3];
    const float* Wa = (const float*)d_in[4];
    const int* src = (const int*)d_in[5];
    const int* dst = (const int*)d_in[6];
    float* h = (float*)d_out;

    // workspace layout
    float* WnT  = (float*)d_ws;                 // 16384
    float* ce   = WnT + 16384;                  // 64
    float* z    = ce + 64;                      // 2,560,000
    float* ssrc = z + (size_t)N_NODES * D_OUT;  // 20000
    float* sdst = ssrc + N_NODES;               // 20000
    float2* es  = (float2*)(sdst + N_NODES);    // 640000 float2 (8B-aligned)
    int* deg     = (int*)(es + N_EDGES);        // 20000
    int* offsets = deg + N_NODES;               // 20001
    int* rank    = offsets + N_NODES + 1;       // 640000

    (void)hipMemsetAsync(deg, 0, N_NODES * sizeof(int), stream);

    k_hist_rank<<<N_EDGES / 256, 256, 0, stream>>>(dst, Wn, We, Wa, deg, rank, WnT, ce);
    k_scan<<<1, 1024, 0, stream>>>(deg, offsets);
    k_zgemm<<<N_NODES / 32, 256, 0, stream>>>(feats_node, WnT, Wa, z, ssrc, sdst);
    k_edge<<<N_EDGES / 64, 256, 0, stream>>>(feats_edge, ce, ssrc, sdst, src, dst, rank, offsets, es);
    k_gather<<<N_NODES / 4, 256, 0, stream>>>(offsets, es, z, h);
}

// Round 6
// 374.788 us; speedup vs baseline: 1.1600x; 1.0562x over previous
//
#include <hip/hip_runtime.h>
#include <hip/hip_bf16.h>

#define N_NODES 20000
#define N_EDGES 640000
#define D_NODE  128
#define D_EDGE  64
#define D_OUT   128

// round-to-nearest-even fp32 -> bf16 bits
__device__ __forceinline__ unsigned short f2bf(float x) {
    unsigned u = __float_as_uint(x);
    unsigned r = ((u >> 16) & 1u) + 0x7FFFu;
    return (unsigned short)((u + r) >> 16);
}
__device__ __forceinline__ float bf2f(unsigned short b) {
    return __uint_as_float((unsigned)b << 16);
}

// ---------------------------------------------------------------------------
// k_init_prep: blocks 0..78 zero deg; block 79 builds WnT (transpose) and
// ce = We^T a_e. Replaces hipMemsetAsync + the old prep, one dispatch.
// ---------------------------------------------------------------------------
__global__ __launch_bounds__(256) void k_init_prep(const float* __restrict__ Wn,
                                                   const float* __restrict__ We,
                                                   const float* __restrict__ Wa,
                                                   int* __restrict__ deg,
                                                   float* __restrict__ WnT,
                                                   float* __restrict__ ce) {
    int t = threadIdx.x, b = blockIdx.x;
    if (b < 79) {
        int i = b * 256 + t;
        if (i < N_NODES) deg[i] = 0;
    } else {
        for (int idx = t; idx < D_OUT * D_NODE; idx += 256) {
            int o = idx >> 7, k = idx & 127;
            WnT[k * D_OUT + o] = Wn[idx];
        }
        if (t < D_EDGE) {
            float a = 0.f;
            for (int o = 0; o < D_OUT; ++o)
                a += Wa[2 * D_OUT + o] * We[o * D_EDGE + t];
            ce[t] = a;
        }
    }
}

// ---------------------------------------------------------------------------
// k_fused: blocks [0,625) = zgemm (z in bf16, fused fp32 ssrc/sdst);
//          blocks [625,3125) = dst histogram + per-edge rank.
// ---------------------------------------------------------------------------
__global__ __launch_bounds__(256) void k_fused(const float* __restrict__ feats,
                                               const float* __restrict__ wT,
                                               const float* __restrict__ Wa,
                                               const int* __restrict__ dst,
                                               unsigned short* __restrict__ zb,
                                               float* __restrict__ ssrc,
                                               float* __restrict__ sdst,
                                               int* __restrict__ deg,
                                               int* __restrict__ rank) {
    __shared__ float sW[64 * 128];
    __shared__ float sF[32 * 128];
    int t = threadIdx.x;

    if (blockIdx.x >= 625) {
        int j = (blockIdx.x - 625) * 256 + t;
        rank[j] = atomicAdd(&deg[dst[j]], 1);
        return;
    }

    int nb = blockIdx.x * 32;
    const float4* fsrc = (const float4*)(feats + (size_t)nb * D_NODE);
    float4* fdst = (float4*)sF;
    for (int i = t; i < 32 * 32; i += 256) fdst[i] = fsrc[i];

    float acc[4][4] = {{0.f}};
    int o0 = (t & 31) * 4;
    int n0 = (t >> 5) * 4;

    for (int p = 0; p < 2; ++p) {
        __syncthreads();
        const float4* wsrc = (const float4*)(wT + p * 64 * 128);
        float4* wdst = (float4*)sW;
        for (int i = t; i < 64 * 32; i += 256) wdst[i] = wsrc[i];
        __syncthreads();
        for (int kk = 0; kk < 64; kk += 4) {
            float4 w0 = *(const float4*)(sW + (kk + 0) * 128 + o0);
            float4 w1 = *(const float4*)(sW + (kk + 1) * 128 + o0);
            float4 w2 = *(const float4*)(sW + (kk + 2) * 128 + o0);
            float4 w3 = *(const float4*)(sW + (kk + 3) * 128 + o0);
#pragma unroll
            for (int j = 0; j < 4; ++j) {
                float4 f = *(const float4*)(sF + (n0 + j) * 128 + p * 64 + kk);
                acc[j][0] += f.x * w0.x + f.y * w1.x + f.z * w2.x + f.w * w3.x;
                acc[j][1] += f.x * w0.y + f.y * w1.y + f.z * w2.y + f.w * w3.y;
                acc[j][2] += f.x * w0.z + f.y * w1.z + f.z * w2.z + f.w * w3.z;
                acc[j][3] += f.x * w0.w + f.y * w1.w + f.z * w2.w + f.w * w3.w;
            }
        }
    }

    float as0 = Wa[o0 + 0], as1 = Wa[o0 + 1], as2 = Wa[o0 + 2], as3 = Wa[o0 + 3];
    float ad0 = Wa[128 + o0 + 0], ad1 = Wa[128 + o0 + 1],
          ad2 = Wa[128 + o0 + 2], ad3 = Wa[128 + o0 + 3];
#pragma unroll
    for (int j = 0; j < 4; ++j) {
        int n = nb + n0 + j;
        ushort4 zo;
        zo.x = f2bf(acc[j][0]); zo.y = f2bf(acc[j][1]);
        zo.z = f2bf(acc[j][2]); zo.w = f2bf(acc[j][3]);
        *(ushort4*)(zb + (size_t)n * D_OUT + o0) = zo;
        float ps = acc[j][0] * as0 + acc[j][1] * as1 + acc[j][2] * as2 + acc[j][3] * as3;
        float pd = acc[j][0] * ad0 + acc[j][1] * ad1 + acc[j][2] * ad2 + acc[j][3] * ad3;
#pragma unroll
        for (int off = 16; off; off >>= 1) {
            ps += __shfl_xor(ps, off, 32);
            pd += __shfl_xor(pd, off, 32);
        }
        if ((t & 31) == 0) { ssrc[n] = ps; sdst[n] = pd; }
    }
}

// ---------------------------------------------------------------------------
// k_scan: single-round thread-coarsened exclusive scan (1024 x 20 elems).
// ---------------------------------------------------------------------------
__global__ __launch_bounds__(1024) void k_scan(const int* __restrict__ deg,
                                               int* __restrict__ offsets) {
    __shared__ int wsum[16];
    __shared__ int woff[16];
    const int PER = 20;
    int t = threadIdx.x, lane = t & 63, wv = t >> 6;
    int base = t * PER;
    int v[PER];
    int tsum = 0;
#pragma unroll
    for (int i = 0; i < PER; ++i) {
        int idx = base + i;
        v[i] = (idx < N_NODES) ? deg[idx] : 0;
        tsum += v[i];
    }
    int x = tsum;
#pragma unroll
    for (int d = 1; d < 64; d <<= 1) {
        int y = __shfl_up(x, d, 64);
        if (lane >= d) x += y;
    }
    if (lane == 63) wsum[wv] = x;
    __syncthreads();
    if (t == 0) {
        int a = 0;
        for (int i = 0; i < 16; ++i) { int tmp = wsum[i]; woff[i] = a; a += tmp; }
        offsets[N_NODES] = a;
    }
    __syncthreads();
    int run = (x - tsum) + woff[wv];
#pragma unroll
    for (int i = 0; i < PER; ++i) {
        int idx = base + i;
        if (idx < N_NODES) offsets[idx] = run;
        run += v[i];
    }
}

// ---------------------------------------------------------------------------
// k_edge: 4 threads per edge, fully coalesced; atomic-free CSR placement
// pos = offsets[dst] + rank. One 8B scatter store {e, src} per edge.
// ---------------------------------------------------------------------------
__global__ __launch_bounds__(256) void k_edge(const float* __restrict__ fe,
                                              const float* __restrict__ ce,
                                              const float* __restrict__ ssrc,
                                              const float* __restrict__ sdst,
                                              const int* __restrict__ src,
                                              const int* __restrict__ dst,
                                              const int* __restrict__ rank,
                                              const int* __restrict__ offsets,
                                              float2* __restrict__ es) {
    int t = threadIdx.x;
    int j = blockIdx.x * 64 + (t >> 2);
    int part = t & 3;
    const float4* row = (const float4*)(fe + (size_t)j * D_EDGE + part * 16);
    const float4* c4 = (const float4*)(ce + part * 16);
    float acc = 0.f;
#pragma unroll
    for (int i = 0; i < 4; ++i) {
        float4 f = row[i];
        float4 c = c4[i];
        acc += f.x * c.x + f.y * c.y + f.z * c.z + f.w * c.w;
    }
    acc += __shfl_xor(acc, 1, 64);
    acc += __shfl_xor(acc, 2, 64);
    if (part == 0) {
        int sj = src[j], dj = dst[j];
        float x = acc + ssrc[sj] + sdst[dj];
        float ev = x > 0.f ? x : 0.2f * x;
        int pos = offsets[dj] + rank[j];
        es[pos] = make_float2(ev, __int_as_float(sj));
    }
}

// ---------------------------------------------------------------------------
// k_gather: one wave per node, zero barriers/LDS. Softmax weights from fp32
// logits; aggregation gathers bf16 z rows (64 lanes x ushort2 = 256B/edge,
// half the fp32 traffic). 4 nodes per 256-thread block.
// ---------------------------------------------------------------------------
__global__ __launch_bounds__(256) void k_gather(const int* __restrict__ offsets,
                                                const float2* __restrict__ es,
                                                const unsigned short* __restrict__ zb,
                                                float* __restrict__ h) {
    int lane = threadIdx.x & 63;
    int n = blockIdx.x * 4 + (threadIdx.x >> 6);
    int beg = offsets[n], end = offsets[n + 1];

    float2 v0 = make_float2(-3.4e38f, 0.f);
    int i0 = beg + lane;
    if (i0 < end) v0 = es[i0];
    float lmax = v0.x;
    for (int base = beg + 64; base < end; base += 64) {
        int i = base + lane;
        lmax = fmaxf(lmax, (i < end) ? es[i].x : -3.4e38f);
    }
#pragma unroll
    for (int off = 32; off; off >>= 1) lmax = fmaxf(lmax, __shfl_xor(lmax, off, 64));
    float m = lmax;

    float w0 = (i0 < end) ? __expf(v0.x - m) : 0.f;
    float lsum = w0;
    for (int base = beg + 64; base < end; base += 64) {
        int i = base + lane;
        lsum += (i < end) ? __expf(es[i].x - m) : 0.f;
    }
#pragma unroll
    for (int off = 32; off; off >>= 1) lsum += __shfl_xor(lsum, off, 64);
    float inv = (lsum > 0.f) ? 1.f / lsum : 0.f;

    float accx = 0.f, accy = 0.f;
    {
        int cnt = min(64, end - beg);
        float wl = w0 * inv;
        int sl = __float_as_int(v0.y);
        int r = 0;
        for (; r + 4 <= cnt; r += 4) {
            float wr0 = __shfl(wl, r + 0, 64); int sr0 = __shfl(sl, r + 0, 64);
            float wr1 = __shfl(wl, r + 1, 64); int sr1 = __shfl(sl, r + 1, 64);
            float wr2 = __shfl(wl, r + 2, 64); int sr2 = __shfl(sl, r + 2, 64);
            float wr3 = __shfl(wl, r + 3, 64); int sr3 = __shfl(sl, r + 3, 64);
            ushort2 z0 = *(const ushort2*)(zb + (size_t)sr0 * D_OUT + lane * 2);
            ushort2 z1 = *(const ushort2*)(zb + (size_t)sr1 * D_OUT + lane * 2);
            ushort2 z2 = *(const ushort2*)(zb + (size_t)sr2 * D_OUT + lane * 2);
            ushort2 z3 = *(const ushort2*)(zb + (size_t)sr3 * D_OUT + lane * 2);
            accx += wr0 * bf2f(z0.x) + wr1 * bf2f(z1.x) + wr2 * bf2f(z2.x) + wr3 * bf2f(z3.x);
            accy += wr0 * bf2f(z0.y) + wr1 * bf2f(z1.y) + wr2 * bf2f(z2.y) + wr3 * bf2f(z3.y);
        }
        for (; r < cnt; ++r) {
            float wr = __shfl(wl, r, 64); int sr = __shfl(sl, r, 64);
            ushort2 zv = *(const ushort2*)(zb + (size_t)sr * D_OUT + lane * 2);
            accx += wr * bf2f(zv.x); accy += wr * bf2f(zv.y);
        }
    }
    for (int base = beg + 64; base < end; base += 64) {
        int i = base + lane;
        float2 v = (i < end) ? es[i] : make_float2(0.f, 0.f);
        float wl = (i < end) ? __expf(v.x - m) * inv : 0.f;
        int sl = __float_as_int(v.y);
        int cnt = min(64, end - base);
        int r = 0;
        for (; r + 4 <= cnt; r += 4) {
            float wr0 = __shfl(wl, r + 0, 64); int sr0 = __shfl(sl, r + 0, 64);
            float wr1 = __shfl(wl, r + 1, 64); int sr1 = __shfl(sl, r + 1, 64);
            float wr2 = __shfl(wl, r + 2, 64); int sr2 = __shfl(sl, r + 2, 64);
            float wr3 = __shfl(wl, r + 3, 64); int sr3 = __shfl(sl, r + 3, 64);
            ushort2 z0 = *(const ushort2*)(zb + (size_t)sr0 * D_OUT + lane * 2);
            ushort2 z1 = *(const ushort2*)(zb + (size_t)sr1 * D_OUT + lane * 2);
            ushort2 z2 = *(const ushort2*)(zb + (size_t)sr2 * D_OUT + lane * 2);
            ushort2 z3 = *(const ushort2*)(zb + (size_t)sr3 * D_OUT + lane * 2);
            accx += wr0 * bf2f(z0.x) + wr1 * bf2f(z1.x) + wr2 * bf2f(z2.x) + wr3 * bf2f(z3.x);
            accy += wr0 * bf2f(z0.y) + wr1 * bf2f(z1.y) + wr2 * bf2f(z2.y) + wr3 * bf2f(z3.y);
        }
        for (; r < cnt; ++r) {
            float wr = __shfl(wl, r, 64); int sr = __shfl(sl, r, 64);
            ushort2 zv = *(const ushort2*)(zb + (size_t)sr * D_OUT + lane * 2);
            accx += wr * bf2f(zv.x); accy += wr * bf2f(zv.y);
        }
    }
    *(float2*)(h + (size_t)n * D_OUT + lane * 2) = make_float2(accx, accy);
}

extern "C" void kernel_launch(void* const* d_in, const int* in_sizes, int n_in,
                              void* d_out, int out_size, void* d_ws, size_t ws_size,
                              hipStream_t stream) {
    const float* feats_node = (const float*)d_in[0];
    const float* feats_edge = (const float*)d_in[1];
    const float* Wn = (const float*)d_in[2];
    const float* We = (const float*)d_in[3];
    const float* Wa = (const float*)d_in[4];
    const int* src = (const int*)d_in[5];
    const int* dst = (const int*)d_in[6];
    float* h = (float*)d_out;

    // workspace layout
    float* WnT  = (float*)d_ws;                       // 16384 f
    float* ce   = WnT + 16384;                        // 64 f
    float* ssrc = ce + 64;                            // 20000 f
    float* sdst = ssrc + N_NODES;                     // 20000 f
    float2* es  = (float2*)(sdst + N_NODES);          // 640000 float2 (8B-aligned)
    unsigned short* zb = (unsigned short*)(es + N_EDGES); // 2,560,000 ushort
    int* deg     = (int*)(zb + (size_t)N_NODES * D_OUT);  // 20000
    int* offsets = deg + N_NODES;                     // 20001
    int* rank    = offsets + N_NODES + 1;             // 640000

    k_init_prep<<<80, 256, 0, stream>>>(Wn, We, Wa, deg, WnT, ce);
    k_fused<<<3125, 256, 0, stream>>>(feats_node, WnT, Wa, dst, zb, ssrc, sdst, deg, rank);
    k_scan<<<1, 1024, 0, stream>>>(deg, offsets);
    k_edge<<<N_EDGES / 64, 256, 0, stream>>>(feats_edge, ce, ssrc, sdst, src, dst, rank, offsets, es);
    k_gather<<<N_NODES / 4, 256, 0, stream>>>(offsets, es, zb, h);
}